// Round 4
// baseline (2628.505 us; speedup 1.0000x reference)
//
#include <hip/hip_runtime.h>
#include <hip/hip_bf16.h>

// ---------------------------------------------------------------------------
// GraphTransformerBlock: TransformerConv(H=2, C=128) + skip + LN + FFN + LN
// R4: latency-optimized fused_attn (no-max softmax, 4-edge chunks with
// double-buffered prefetch, kv-interleaved single 16B gather, int2(e,src)
// CSR); econ as one bf16 MFMA ADD dispatch; all weight prep in one kernel.
// O1 row [1024]: q 0-255 | kv-interleaved 256-767 | skip 768-895 | P 896-959
//   kv region: for g=0..63 (g=h*32+hl): [256+g*8 .. +3]=k[h][hl*4..], [+4..+7]=v
// ---------------------------------------------------------------------------

typedef __attribute__((ext_vector_type(8))) short bf16x8;
typedef __attribute__((ext_vector_type(8))) unsigned short u16x8;
typedef __attribute__((ext_vector_type(4))) float f32x4;

__device__ __forceinline__ float bf2f(unsigned short u) {
    union { float f; unsigned u32; } x; x.u32 = ((unsigned)u) << 16; return x.f;
}
__device__ __forceinline__ unsigned short f2bf(float f) {
    unsigned u = __float_as_uint(f);
    return (unsigned short)((u + 0x7FFFu + ((u >> 16) & 1u)) >> 16);
}

// ---------------- bf16 MFMA GEMM: C[M,OC] = act(A[M,K] @ W[OC,K]^T + bias) --
// 128x128 tile, BK=32, 4 waves; OC = gridDim.x*128 (exact), M guarded.
template<int ACT, int OUT_BF16, int ADD>
__global__ __launch_bounds__(256)
void gemm_mfma(const unsigned short* __restrict__ A, int lda,
               const unsigned short* __restrict__ W, int ldw,
               const float* __restrict__ bias,
               void* __restrict__ outp, int ldo, int M, int K) {
    __shared__ unsigned short As[128 * 40];   // pitch 40 elems (80B) kills conflicts
    __shared__ unsigned short Bs[128 * 40];
    const int tid = threadIdx.x;
    const int wave = tid >> 6, lane = tid & 63;
    const int row0 = blockIdx.y * 128, col0 = blockIdx.x * 128;
    const int srow = tid >> 2;        // 0..63
    const int skg  = (tid & 3) * 8;   // k element offset of 16B chunk
    int r0 = row0 + srow;      if (r0 >= M) r0 = 0;
    int r1 = row0 + srow + 64; if (r1 >= M) r1 = 0;
    const int b0 = col0 + srow, b1 = col0 + srow + 64;

    f32x4 acc[2][8];
    const f32x4 z4 = {0.f, 0.f, 0.f, 0.f};
    #pragma unroll
    for (int i = 0; i < 2; i++)
        #pragma unroll
        for (int j = 0; j < 8; j++) acc[i][j] = z4;

    const int mrow = wave * 32 + (lane & 15);
    const int kq = (lane >> 4) * 8;

    for (int kt = 0; kt < K; kt += 32) {
        float4 a0 = *(const float4*)(A + (size_t)r0 * lda + kt + skg);
        float4 a1 = *(const float4*)(A + (size_t)r1 * lda + kt + skg);
        float4 w0 = *(const float4*)(W + (size_t)b0 * ldw + kt + skg);
        float4 w1 = *(const float4*)(W + (size_t)b1 * ldw + kt + skg);
        __syncthreads();
        *(float4*)&As[srow * 40 + skg]        = a0;
        *(float4*)&As[(srow + 64) * 40 + skg] = a1;
        *(float4*)&Bs[srow * 40 + skg]        = w0;
        *(float4*)&Bs[(srow + 64) * 40 + skg] = w1;
        __syncthreads();
        bf16x8 af0 = *(const bf16x8*)&As[mrow * 40 + kq];
        bf16x8 af1 = *(const bf16x8*)&As[(mrow + 16) * 40 + kq];
        bf16x8 bfr[8];
        #pragma unroll
        for (int j = 0; j < 8; j++)
            bfr[j] = *(const bf16x8*)&Bs[(j * 16 + (lane & 15)) * 40 + kq];
        #pragma unroll
        for (int j = 0; j < 8; j++) {
            acc[0][j] = __builtin_amdgcn_mfma_f32_16x16x32_bf16(af0, bfr[j], acc[0][j], 0, 0, 0);
            acc[1][j] = __builtin_amdgcn_mfma_f32_16x16x32_bf16(af1, bfr[j], acc[1][j], 0, 0, 0);
        }
    }

    // C/D layout: col = lane&15, row = (lane>>4)*4 + reg   [m89/m91 verified]
    const int orow0 = row0 + wave * 32 + ((lane >> 4) << 2);
    const int ocol0 = col0 + (lane & 15);
    #pragma unroll
    for (int i = 0; i < 2; i++) {
        #pragma unroll
        for (int r = 0; r < 4; r++) {
            int row = orow0 + i * 16 + r;
            if (row >= M) continue;
            #pragma unroll
            for (int j = 0; j < 8; j++) {
                int col = ocol0 + j * 16;
                float v = acc[i][j][r] + (bias ? bias[col] : 0.f);
                if (ACT == 1) v = (v > 0.f) ? v : 0.01f * v;
                if (OUT_BF16)      ((unsigned short*)outp)[(size_t)row * ldo + col] = f2bf(v);
                else if (ADD)      ((float*)outp)[(size_t)row * ldo + col] += v;
                else               ((float*)outp)[(size_t)row * ldo + col] = v;
            }
        }
    }
}

// ---------------- unified weight prep ---------------------------------------
// seg0 Wcat[1024][128] bf16 (kv-interleaved rows + folded Wcomb)
// seg1 bcat[1024] f32 | seg2 W1h | seg3 W2h | seg4 Wec[256][64] bf16
__global__ void prep_weights(const float* __restrict__ Wq, const float* __restrict__ bq,
                             const float* __restrict__ Wk, const float* __restrict__ bk,
                             const float* __restrict__ Wv, const float* __restrict__ bv,
                             const float* __restrict__ We, const float* __restrict__ Wsk,
                             const float* __restrict__ bsk,
                             const float* __restrict__ W1, const float* __restrict__ W2,
                             unsigned short* __restrict__ Wcat, float* __restrict__ bcat,
                             unsigned short* __restrict__ W1h, unsigned short* __restrict__ W2h,
                             unsigned short* __restrict__ Wec) {
    int i = blockIdx.x * 256 + threadIdx.x;
    if (i < 131072) {                       // Wcat
        int oc = i >> 7, r = i & 127;
        float v;
        if (oc < 256) v = Wq[(size_t)oc * 128 + r];
        else if (oc < 768) {
            int rr = oc - 256, g = rr >> 3, p = rr & 7;
            int h = g >> 5, ch = h * 128 + (g & 31) * 4 + (p & 3);
            v = (p < 4) ? Wk[(size_t)ch * 128 + r] : Wv[(size_t)ch * 128 + r];
        } else if (oc < 896) v = Wsk[(size_t)(oc - 768) * 128 + r];
        else if (oc < 960) {
            int qd = oc - 896, h = qd >> 5, t = qd & 31;
            float s = 0.f;
            for (int c = 0; c < 128; c++)
                s += Wq[(size_t)(h*128 + c) * 128 + r] * We[(size_t)(h*128 + c) * 32 + t];
            v = s;
        } else v = 0.f;
        Wcat[i] = f2bf(v);
    } else if (i < 132096) {                // bcat
        int oc = i - 131072;
        float v;
        if (oc < 256) v = bq[oc];
        else if (oc < 768) {
            int rr = oc - 256, g = rr >> 3, p = rr & 7;
            int ch = (g >> 5) * 128 + (g & 31) * 4 + (p & 3);
            v = (p < 4) ? bk[ch] : bv[ch];
        } else if (oc < 896) v = bsk[oc - 768];
        else if (oc < 960) {
            int qd = oc - 896, h = qd >> 5, t = qd & 31;
            float s = 0.f;
            for (int c = 0; c < 128; c++)
                s += bq[h*128 + c] * We[(size_t)(h*128 + c) * 32 + t];
            v = s;
        } else v = 0.f;
        bcat[oc] = v;
    } else if (i < 164864) {                // W1h
        int j = i - 132096;
        W1h[j] = f2bf(W1[j]);
    } else if (i < 197632) {                // W2h
        int j = i - 164864;
        W2h[j] = f2bf(W2[j]);
    } else if (i < 214016) {                // Wec block-diag [256][64]
        int j = i - 197632;
        int oc = j >> 6, t = j & 63;
        int h = oc >> 7, c = oc & 127;
        float v = 0.f;
        if (t >= h * 32 && t < h * 32 + 32)
            v = We[(size_t)(h * 128 + c) * 32 + (t - h * 32)];
        Wec[j] = f2bf(v);
    }
}

__global__ void f32_to_bf16(const float* __restrict__ in, unsigned short* __restrict__ out, int n) {
    int i = blockIdx.x * blockDim.x + threadIdx.x;
    if (i < n) out[i] = f2bf(in[i]);
}

// ---------------- CSR build -------------------------------------------------
__global__ void zero_int(int* __restrict__ p, int n) {
    int i = blockIdx.x * blockDim.x + threadIdx.x;
    if (i < n) p[i] = 0;
}
__global__ void deg_count(const int* __restrict__ dst, int* __restrict__ deg, int E) {
    int e = blockIdx.x * blockDim.x + threadIdx.x;
    if (e < E) atomicAdd(&deg[dst[e]], 1);
}
__global__ __launch_bounds__(256)
void scan_block(const int* __restrict__ deg, int* __restrict__ tmp,
                int* __restrict__ bsum, int n) {
    __shared__ int lds[256];
    int i = blockIdx.x * 256 + threadIdx.x;
    int v = (i < n) ? deg[i] : 0;
    lds[threadIdx.x] = v;
    __syncthreads();
    #pragma unroll
    for (int off = 1; off < 256; off <<= 1) {
        int t = (threadIdx.x >= off) ? lds[threadIdx.x - off] : 0;
        __syncthreads();
        lds[threadIdx.x] += t;
        __syncthreads();
    }
    if (i < n) tmp[i] = lds[threadIdx.x];
    if (threadIdx.x == 255) bsum[blockIdx.x] = lds[255];
}
__global__ __launch_bounds__(1024)
void scan_bsum(int* __restrict__ bsum, int nb) {
    __shared__ int lds[1024];
    int v = (threadIdx.x < nb) ? bsum[threadIdx.x] : 0;
    lds[threadIdx.x] = v;
    __syncthreads();
    #pragma unroll
    for (int off = 1; off < 1024; off <<= 1) {
        int t = (threadIdx.x >= off) ? lds[threadIdx.x - off] : 0;
        __syncthreads();
        lds[threadIdx.x] += t;
        __syncthreads();
    }
    if (threadIdx.x < nb) bsum[threadIdx.x] = lds[threadIdx.x] - v;  // exclusive
}
__global__ __launch_bounds__(256)
void scan_finalize(const int* __restrict__ tmp, const int* __restrict__ bsum,
                   int* __restrict__ row, int n) {
    int i = blockIdx.x * 256 + threadIdx.x;
    if (i < n) row[i + 1] = tmp[i] + bsum[blockIdx.x];
    if (i == 0) row[0] = 0;
}
__global__ void csr_fill(const int* __restrict__ src, const int* __restrict__ dst,
                         const int* __restrict__ row, int* __restrict__ cnt,
                         int2* __restrict__ eid2, int E) {
    int e = blockIdx.x * blockDim.x + threadIdx.x;
    if (e < E) {
        int d = dst[e];
        int pos = row[d] + atomicAdd(&cnt[d], 1);
        eid2[pos] = make_int2(e, src[e]);
    }
}

// ---------------- fused attention: no-max softmax, chunked prefetch ---------
__global__ __launch_bounds__(256)
void fused_attn(const unsigned short* __restrict__ O1, const float* __restrict__ EA,
                const int* __restrict__ row, const int2* __restrict__ eid2,
                float* __restrict__ agg, unsigned short* __restrict__ weab, int N) {
    int node = blockIdx.x * 4 + (threadIdx.x >> 6);
    if (node >= N) return;
    const int lane = threadIdx.x & 63;
    const int h = lane >> 5, hl = lane & 31;
    const int choff = h * 128 + hl * 4;
    const float inv = 0.08838834764831845f;  // 1/sqrt(128)

    ushort4 q4 = *(const ushort4*)(O1 + (size_t)node * 1024 + choff);
    float4 qv = make_float4(bf2f(q4.x), bf2f(q4.y), bf2f(q4.z), bf2f(q4.w));
    float pd = bf2f(O1[(size_t)node * 1024 + 896 + lane]);

    const int j0 = row[node], jend = row[node + 1];
    float l = 0.f, wacc = 0.f;
    float4 acc = make_float4(0.f, 0.f, 0.f, 0.f);

    u16x8 kvb[2][4];
    float eab[2][4];
    const u16x8 zkv = {0,0,0,0,0,0,0,0};

    auto load_chunk = [&](int buf, int base) {
        #pragma unroll
        for (int p = 0; p < 4; p++) {
            int j = base + p;
            if (j < jend) {
                int2 es = eid2[j];
                kvb[buf][p] = *(const u16x8*)(O1 + (size_t)es.y * 1024 + 256 + lane * 8);
                eab[buf][p] = EA[(size_t)es.x * 32 + hl];
            } else { kvb[buf][p] = zkv; eab[buf][p] = 0.f; }
        }
    };

    int base = j0, cur = 0;
    if (base < jend) load_chunk(0, base);
    while (base < jend) {
        if (base + 4 < jend) load_chunk(cur ^ 1, base + 4);
        float d[4];
        #pragma unroll
        for (int p = 0; p < 4; p++) {
            u16x8 kv = kvb[cur][p];
            d[p] = qv.x * bf2f(kv[0]) + qv.y * bf2f(kv[1])
                 + qv.z * bf2f(kv[2]) + qv.w * bf2f(kv[3])
                 + pd * eab[cur][p];
        }
        #pragma unroll
        for (int off = 16; off >= 1; off >>= 1) {
            #pragma unroll
            for (int p = 0; p < 4; p++) d[p] += __shfl_xor(d[p], off);
        }
        #pragma unroll
        for (int p = 0; p < 4; p++) {
            float w = (base + p < jend) ? __expf(d[p] * inv) : 0.f;
            u16x8 kv = kvb[cur][p];
            l += w;
            acc.x += w * bf2f(kv[4]);
            acc.y += w * bf2f(kv[5]);
            acc.z += w * bf2f(kv[6]);
            acc.w += w * bf2f(kv[7]);
            wacc += w * eab[cur][p];
        }
        base += 4; cur ^= 1;
    }
    float r = 1.f / (l + 1e-16f);
    acc.x *= r; acc.y *= r; acc.z *= r; acc.w *= r;
    *(float4*)(agg + (size_t)node * 256 + choff) = acc;
    weab[(size_t)node * 64 + lane] = f2bf(wacc * r);
}

// ---------------- LayerNorm passes ------------------------------------------
__global__ __launch_bounds__(256)
void node_ln1(const float* __restrict__ x, const float* __restrict__ agg,
              const unsigned short* __restrict__ O1, const float* __restrict__ g,
              const float* __restrict__ b, unsigned short* __restrict__ hout, int N) {
    int node = blockIdx.x * 4 + (threadIdx.x >> 6);
    if (node >= N) return;
    int lane = threadIdx.x & 63;
    float2 xv = ((const float2*)(x   + (size_t)node*128))[lane];
    float2 a0 = ((const float2*)(agg + (size_t)node*256))[lane];
    float2 a1 = ((const float2*)(agg + (size_t)node*256 + 128))[lane];
    ushort2 s2 = *(const ushort2*)(O1 + (size_t)node*1024 + 768 + lane*2);
    float t0 = xv.x + 0.5f*(a0.x + a1.x) + bf2f(s2.x);
    float t1 = xv.y + 0.5f*(a0.y + a1.y) + bf2f(s2.y);
    float s = t0 + t1;
    #pragma unroll
    for (int off = 32; off >= 1; off >>= 1) s += __shfl_xor(s, off);
    float mu = s * (1.f/128.f);
    float d0 = t0 - mu, d1 = t1 - mu;
    float q = d0*d0 + d1*d1;
    #pragma unroll
    for (int off = 32; off >= 1; off >>= 1) q += __shfl_xor(q, off);
    float rs = rsqrtf(q * (1.f/128.f) + 1e-5f);
    float2 gv = ((const float2*)g)[lane], bv = ((const float2*)b)[lane];
    ushort2 o;
    o.x = f2bf(d0*rs*gv.x + bv.x);
    o.y = f2bf(d1*rs*gv.y + bv.y);
    *(ushort2*)(hout + (size_t)node*128 + lane*2) = o;
}

__global__ __launch_bounds__(256)
void node_ln2(const unsigned short* __restrict__ hb, const float* __restrict__ f,
              const float* __restrict__ g, const float* __restrict__ b,
              float* __restrict__ out, int N) {
    int node = blockIdx.x * 4 + (threadIdx.x >> 6);
    if (node >= N) return;
    int lane = threadIdx.x & 63;
    ushort2 h2 = *(const ushort2*)(hb + (size_t)node*128 + lane*2);
    float2 fv = ((const float2*)(f + (size_t)node*128))[lane];
    float t0 = bf2f(h2.x) + fv.x;
    float t1 = bf2f(h2.y) + fv.y;
    float s = t0 + t1;
    #pragma unroll
    for (int off = 32; off >= 1; off >>= 1) s += __shfl_xor(s, off);
    float mu = s * (1.f/128.f);
    float d0 = t0 - mu, d1 = t1 - mu;
    float q = d0*d0 + d1*d1;
    #pragma unroll
    for (int off = 32; off >= 1; off >>= 1) q += __shfl_xor(q, off);
    float rs = rsqrtf(q * (1.f/128.f) + 1e-5f);
    float2 gv = ((const float2*)g)[lane], bv = ((const float2*)b)[lane];
    float2 o;
    o.x = d0*rs*gv.x + bv.x;
    o.y = d1*rs*gv.y + bv.y;
    ((float2*)(out + (size_t)node*128))[lane] = o;
}

// ---------------------------------------------------------------------------
extern "C" void kernel_launch(void* const* d_in, const int* in_sizes, int n_in,
                              void* d_out, int out_size, void* d_ws, size_t ws_size,
                              hipStream_t stream) {
    const float* x    = (const float*)d_in[0];
    const int*   ei   = (const int*)d_in[1];
    const float* ea   = (const float*)d_in[2];
    const float* Wq   = (const float*)d_in[3];
    const float* bq   = (const float*)d_in[4];
    const float* Wk   = (const float*)d_in[5];
    const float* bk   = (const float*)d_in[6];
    const float* Wv   = (const float*)d_in[7];
    const float* bv   = (const float*)d_in[8];
    const float* We   = (const float*)d_in[9];
    const float* Wsk  = (const float*)d_in[10];
    const float* bsk  = (const float*)d_in[11];
    const float* g1   = (const float*)d_in[12];
    const float* b1l  = (const float*)d_in[13];
    const float* W1   = (const float*)d_in[14];
    const float* b1f  = (const float*)d_in[15];
    const float* W2   = (const float*)d_in[16];
    const float* b2f  = (const float*)d_in[17];
    const float* g2   = (const float*)d_in[18];
    const float* b2l  = (const float*)d_in[19];
    float* out = (float*)d_out;

    const int N = in_sizes[0] / 128;
    const int E = in_sizes[2] / 32;
    const int* src = ei;
    const int* dst = ei + E;

    char* w = (char*)d_ws;
    unsigned short* O1   = (unsigned short*)w;  w += (size_t)N * 2048;  // [N,1024] bf16
    float* agg           = (float*)w;           w += (size_t)N * 1024;  // [N,256] f32
    unsigned short* weab = (unsigned short*)w;  w += (size_t)N * 128;   // [N,64] bf16
    unsigned short* xh   = (unsigned short*)w;  w += (size_t)N * 256;   // [N,128] bf16
    unsigned short* hb   = (unsigned short*)w;  w += (size_t)N * 256;   // [N,128] bf16
    unsigned short* Wcat = (unsigned short*)w;  w += 1024 * 128 * 2;
    float* bcat          = (float*)w;           w += 1024 * 4;
    unsigned short* W1h  = (unsigned short*)w;  w += 256 * 128 * 2;
    unsigned short* W2h  = (unsigned short*)w;  w += 128 * 256 * 2;
    unsigned short* Wec  = (unsigned short*)w;  w += 256 * 64 * 2;
    int2* eid2           = (int2*)w;            w += (size_t)E * 8;
    int* deg  = (int*)w;
    int* cnt  = deg + N;
    int* tmp  = cnt + N;
    int* rowp = tmp + N;            // N+1
    int* bsum = rowp + N + 1;       // <=1024

    // mid (bf16 [N,256]) and f (f32 [N,128]) alias agg (free after LN1)
    unsigned short* mid = (unsigned short*)agg;
    float* fbuf = (float*)((char*)agg + (size_t)N * 512);

    const int gy128 = (N + 127) / 128;
    const int nb  = (N + 255) / 256;

    // ---- prep ----
    f32_to_bf16<<<(N*128 + 255)/256, 256, 0, stream>>>(x, xh, N*128);
    prep_weights<<<836, 256, 0, stream>>>(Wq, bq, Wk, bk, Wv, bv, We, Wsk, bsk,
                                          W1, W2, Wcat, bcat, W1h, W2h, Wec);

    // ---- fused projection GEMM: O1 = xh @ Wcat^T + bcat ----
    gemm_mfma<0,1,0><<<dim3(8, gy128), 256, 0, stream>>>(xh, 128, Wcat, 128, bcat,
                                                         O1, 1024, N, 128);

    // ---- CSR build ----
    zero_int<<<(2*N + 255)/256, 256, 0, stream>>>(deg, 2*N);   // deg + cnt
    deg_count<<<(E + 255)/256, 256, 0, stream>>>(dst, deg, E);
    scan_block<<<nb, 256, 0, stream>>>(deg, tmp, bsum, N);
    scan_bsum<<<1, 1024, 0, stream>>>(bsum, nb);
    scan_finalize<<<nb, 256, 0, stream>>>(tmp, bsum, rowp, N);
    csr_fill<<<(E + 255)/256, 256, 0, stream>>>(src, dst, rowp, cnt, eid2, E);

    // ---- attention ----
    fused_attn<<<(N + 3)/4, 256, 0, stream>>>(O1, ea, rowp, eid2, agg, weab, N);

    // e-contribution: agg += weab[N,64] @ Wec^T  (block-diag), one MFMA dispatch
    gemm_mfma<0,0,1><<<dim3(2, gy128), 256, 0, stream>>>(weab, 64, Wec, 64, nullptr,
                                                         agg, 256, N, 64);

    // h = LN1(x + mean_heads(agg) + skip) -> bf16
    node_ln1<<<(N + 3)/4, 256, 0, stream>>>(x, agg, O1, g1, b1l, hb, N);

    // FFN (bf16 MFMA)
    gemm_mfma<1,1,0><<<dim3(2, gy128), 256, 0, stream>>>(hb, 128, W1h, 128, b1f,
                                                         mid, 256, N, 128);
    gemm_mfma<0,0,0><<<dim3(1, gy128), 256, 0, stream>>>(mid, 256, W2h, 256, b2f,
                                                         fbuf, 128, N, 256);

    // out = LN2(h + f)
    node_ln2<<<(N + 3)/4, 256, 0, stream>>>(hb, fbuf, g2, b2l, out, N);
}

// Round 5
// 478.621 us; speedup vs baseline: 5.4918x; 5.4918x over previous
//
#include <hip/hip_runtime.h>
#include <hip/hip_bf16.h>

// ---------------------------------------------------------------------------
// GraphTransformerBlock: TransformerConv(H=2, C=128) + skip + LN + FFN + LN
// R5: fused_attn rewritten as statically-register ping-pong pipeline
// (R4's runtime-indexed buffer spilled to scratch -> 16x regression).
// O1 row [1024]: q 0-255 | kv-interleaved 256-767 | skip 768-895 | P 896-959
//   kv region: for g=0..63 (g=h*32+hl): [256+g*8 .. +3]=k[h][hl*4..], [+4..+7]=v
// ---------------------------------------------------------------------------

typedef __attribute__((ext_vector_type(8))) short bf16x8;
typedef __attribute__((ext_vector_type(8))) unsigned short u16x8;
typedef __attribute__((ext_vector_type(4))) float f32x4;

__device__ __forceinline__ float bf2f(unsigned short u) {
    union { float f; unsigned u32; } x; x.u32 = ((unsigned)u) << 16; return x.f;
}
__device__ __forceinline__ unsigned short f2bf(float f) {
    unsigned u = __float_as_uint(f);
    return (unsigned short)((u + 0x7FFFu + ((u >> 16) & 1u)) >> 16);
}

// ---------------- bf16 MFMA GEMM: C[M,OC] = act(A[M,K] @ W[OC,K]^T + bias) --
// 128x128 tile, BK=32, 4 waves; OC = gridDim.x*128 (exact), M guarded.
template<int ACT, int OUT_BF16, int ADD>
__global__ __launch_bounds__(256)
void gemm_mfma(const unsigned short* __restrict__ A, int lda,
               const unsigned short* __restrict__ W, int ldw,
               const float* __restrict__ bias,
               void* __restrict__ outp, int ldo, int M, int K) {
    __shared__ unsigned short As[128 * 40];   // pitch 40 elems (80B) kills conflicts
    __shared__ unsigned short Bs[128 * 40];
    const int tid = threadIdx.x;
    const int wave = tid >> 6, lane = tid & 63;
    const int row0 = blockIdx.y * 128, col0 = blockIdx.x * 128;
    const int srow = tid >> 2;        // 0..63
    const int skg  = (tid & 3) * 8;   // k element offset of 16B chunk
    int r0 = row0 + srow;      if (r0 >= M) r0 = 0;
    int r1 = row0 + srow + 64; if (r1 >= M) r1 = 0;
    const int b0 = col0 + srow, b1 = col0 + srow + 64;

    f32x4 acc[2][8];
    const f32x4 z4 = {0.f, 0.f, 0.f, 0.f};
    #pragma unroll
    for (int i = 0; i < 2; i++)
        #pragma unroll
        for (int j = 0; j < 8; j++) acc[i][j] = z4;

    const int mrow = wave * 32 + (lane & 15);
    const int kq = (lane >> 4) * 8;

    for (int kt = 0; kt < K; kt += 32) {
        float4 a0 = *(const float4*)(A + (size_t)r0 * lda + kt + skg);
        float4 a1 = *(const float4*)(A + (size_t)r1 * lda + kt + skg);
        float4 w0 = *(const float4*)(W + (size_t)b0 * ldw + kt + skg);
        float4 w1 = *(const float4*)(W + (size_t)b1 * ldw + kt + skg);
        __syncthreads();
        *(float4*)&As[srow * 40 + skg]        = a0;
        *(float4*)&As[(srow + 64) * 40 + skg] = a1;
        *(float4*)&Bs[srow * 40 + skg]        = w0;
        *(float4*)&Bs[(srow + 64) * 40 + skg] = w1;
        __syncthreads();
        bf16x8 af0 = *(const bf16x8*)&As[mrow * 40 + kq];
        bf16x8 af1 = *(const bf16x8*)&As[(mrow + 16) * 40 + kq];
        bf16x8 bfr[8];
        #pragma unroll
        for (int j = 0; j < 8; j++)
            bfr[j] = *(const bf16x8*)&Bs[(j * 16 + (lane & 15)) * 40 + kq];
        #pragma unroll
        for (int j = 0; j < 8; j++) {
            acc[0][j] = __builtin_amdgcn_mfma_f32_16x16x32_bf16(af0, bfr[j], acc[0][j], 0, 0, 0);
            acc[1][j] = __builtin_amdgcn_mfma_f32_16x16x32_bf16(af1, bfr[j], acc[1][j], 0, 0, 0);
        }
    }

    // C/D layout: col = lane&15, row = (lane>>4)*4 + reg   [m89/m91 verified]
    const int orow0 = row0 + wave * 32 + ((lane >> 4) << 2);
    const int ocol0 = col0 + (lane & 15);
    #pragma unroll
    for (int i = 0; i < 2; i++) {
        #pragma unroll
        for (int r = 0; r < 4; r++) {
            int row = orow0 + i * 16 + r;
            if (row >= M) continue;
            #pragma unroll
            for (int j = 0; j < 8; j++) {
                int col = ocol0 + j * 16;
                float v = acc[i][j][r] + (bias ? bias[col] : 0.f);
                if (ACT == 1) v = (v > 0.f) ? v : 0.01f * v;
                if (OUT_BF16)      ((unsigned short*)outp)[(size_t)row * ldo + col] = f2bf(v);
                else if (ADD)      ((float*)outp)[(size_t)row * ldo + col] += v;
                else               ((float*)outp)[(size_t)row * ldo + col] = v;
            }
        }
    }
}

// ---------------- unified weight prep ---------------------------------------
__global__ void prep_weights(const float* __restrict__ Wq, const float* __restrict__ bq,
                             const float* __restrict__ Wk, const float* __restrict__ bk,
                             const float* __restrict__ Wv, const float* __restrict__ bv,
                             const float* __restrict__ We, const float* __restrict__ Wsk,
                             const float* __restrict__ bsk,
                             const float* __restrict__ W1, const float* __restrict__ W2,
                             unsigned short* __restrict__ Wcat, float* __restrict__ bcat,
                             unsigned short* __restrict__ W1h, unsigned short* __restrict__ W2h,
                             unsigned short* __restrict__ Wec) {
    int i = blockIdx.x * 256 + threadIdx.x;
    if (i < 131072) {                       // Wcat
        int oc = i >> 7, r = i & 127;
        float v;
        if (oc < 256) v = Wq[(size_t)oc * 128 + r];
        else if (oc < 768) {
            int rr = oc - 256, g = rr >> 3, p = rr & 7;
            int h = g >> 5, ch = h * 128 + (g & 31) * 4 + (p & 3);
            v = (p < 4) ? Wk[(size_t)ch * 128 + r] : Wv[(size_t)ch * 128 + r];
        } else if (oc < 896) v = Wsk[(size_t)(oc - 768) * 128 + r];
        else if (oc < 960) {
            int qd = oc - 896, h = qd >> 5, t = qd & 31;
            float s = 0.f;
            for (int c = 0; c < 128; c++)
                s += Wq[(size_t)(h*128 + c) * 128 + r] * We[(size_t)(h*128 + c) * 32 + t];
            v = s;
        } else v = 0.f;
        Wcat[i] = f2bf(v);
    } else if (i < 132096) {                // bcat
        int oc = i - 131072;
        float v;
        if (oc < 256) v = bq[oc];
        else if (oc < 768) {
            int rr = oc - 256, g = rr >> 3, p = rr & 7;
            int ch = (g >> 5) * 128 + (g & 31) * 4 + (p & 3);
            v = (p < 4) ? bk[ch] : bv[ch];
        } else if (oc < 896) v = bsk[oc - 768];
        else if (oc < 960) {
            int qd = oc - 896, h = qd >> 5, t = qd & 31;
            float s = 0.f;
            for (int c = 0; c < 128; c++)
                s += bq[h*128 + c] * We[(size_t)(h*128 + c) * 32 + t];
            v = s;
        } else v = 0.f;
        bcat[oc] = v;
    } else if (i < 164864) {                // W1h
        int j = i - 132096;
        W1h[j] = f2bf(W1[j]);
    } else if (i < 197632) {                // W2h
        int j = i - 164864;
        W2h[j] = f2bf(W2[j]);
    } else if (i < 214016) {                // Wec block-diag [256][64]
        int j = i - 197632;
        int oc = j >> 6, t = j & 63;
        int h = oc >> 7, c = oc & 127;
        float v = 0.f;
        if (t >= h * 32 && t < h * 32 + 32)
            v = We[(size_t)(h * 128 + c) * 32 + (t - h * 32)];
        Wec[j] = f2bf(v);
    }
}

__global__ void f32_to_bf16(const float* __restrict__ in, unsigned short* __restrict__ out, int n) {
    int i = blockIdx.x * blockDim.x + threadIdx.x;
    if (i < n) out[i] = f2bf(in[i]);
}

// ---------------- CSR build -------------------------------------------------
__global__ void zero_int(int* __restrict__ p, int n) {
    int i = blockIdx.x * blockDim.x + threadIdx.x;
    if (i < n) p[i] = 0;
}
__global__ void deg_count(const int* __restrict__ dst, int* __restrict__ deg, int E) {
    int e = blockIdx.x * blockDim.x + threadIdx.x;
    if (e < E) atomicAdd(&deg[dst[e]], 1);
}
__global__ __launch_bounds__(256)
void scan_block(const int* __restrict__ deg, int* __restrict__ tmp,
                int* __restrict__ bsum, int n) {
    __shared__ int lds[256];
    int i = blockIdx.x * 256 + threadIdx.x;
    int v = (i < n) ? deg[i] : 0;
    lds[threadIdx.x] = v;
    __syncthreads();
    #pragma unroll
    for (int off = 1; off < 256; off <<= 1) {
        int t = (threadIdx.x >= off) ? lds[threadIdx.x - off] : 0;
        __syncthreads();
        lds[threadIdx.x] += t;
        __syncthreads();
    }
    if (i < n) tmp[i] = lds[threadIdx.x];
    if (threadIdx.x == 255) bsum[blockIdx.x] = lds[255];
}
__global__ __launch_bounds__(1024)
void scan_bsum(int* __restrict__ bsum, int nb) {
    __shared__ int lds[1024];
    int v = (threadIdx.x < nb) ? bsum[threadIdx.x] : 0;
    lds[threadIdx.x] = v;
    __syncthreads();
    #pragma unroll
    for (int off = 1; off < 1024; off <<= 1) {
        int t = (threadIdx.x >= off) ? lds[threadIdx.x - off] : 0;
        __syncthreads();
        lds[threadIdx.x] += t;
        __syncthreads();
    }
    if (threadIdx.x < nb) bsum[threadIdx.x] = lds[threadIdx.x] - v;  // exclusive
}
__global__ __launch_bounds__(256)
void scan_finalize(const int* __restrict__ tmp, const int* __restrict__ bsum,
                   int* __restrict__ row, int n) {
    int i = blockIdx.x * 256 + threadIdx.x;
    if (i < n) row[i + 1] = tmp[i] + bsum[blockIdx.x];
    if (i == 0) row[0] = 0;
}
__global__ void csr_fill(const int* __restrict__ src, const int* __restrict__ dst,
                         const int* __restrict__ row, int* __restrict__ cnt,
                         int2* __restrict__ eid2, int E) {
    int e = blockIdx.x * blockDim.x + threadIdx.x;
    if (e < E) {
        int d = dst[e];
        int pos = row[d] + atomicAdd(&cnt[d], 1);
        eid2[pos] = make_int2(e, src[e]);
    }
}

// ---------------- fused attention: static ping-pong pipeline ----------------
// 2 edges/chunk; kv prefetched 1 chunk ahead, eid2 indices 2 chunks ahead.
// Every buffer index is compile-time (phase-unrolled) -> no scratch.
__global__ __launch_bounds__(256)
void fused_attn(const unsigned short* __restrict__ O1, const float* __restrict__ EA,
                const int* __restrict__ row, const int2* __restrict__ eid2,
                float* __restrict__ agg, unsigned short* __restrict__ weab, int N) {
    int node = blockIdx.x * 4 + (threadIdx.x >> 6);
    if (node >= N) return;
    const int lane = threadIdx.x & 63;
    const int hl = lane & 31;
    const int choff = (lane >> 5) * 128 + (hl << 2);
    const float inv = 0.08838834764831845f;  // 1/sqrt(128)

    ushort4 q4 = *(const ushort4*)(O1 + (size_t)node * 1024 + choff);
    float4 qv = make_float4(bf2f(q4.x), bf2f(q4.y), bf2f(q4.z), bf2f(q4.w));
    float pd = bf2f(O1[(size_t)node * 1024 + 896 + lane]);

    const int j0 = row[node], jend = row[node + 1];
    float l = 0.f, wacc = 0.f;
    float4 acc = make_float4(0.f, 0.f, 0.f, 0.f);

    const u16x8 zkv = {0,0,0,0,0,0,0,0};
    u16x8 kvA0, kvA1, kvB0, kvB1;
    float eaA0, eaA1, eaB0, eaB1;
    int2 es0, es1;

    // chunk 0 data -> A
    if (j0 < jend) {
        int2 es = eid2[j0];
        kvA0 = *(const u16x8*)(O1 + (size_t)es.y * 1024 + 256 + lane * 8);
        eaA0 = EA[(size_t)es.x * 32 + hl];
    } else { kvA0 = zkv; eaA0 = 0.f; }
    if (j0 + 1 < jend) {
        int2 es = eid2[j0 + 1];
        kvA1 = *(const u16x8*)(O1 + (size_t)es.y * 1024 + 256 + lane * 8);
        eaA1 = EA[(size_t)es.x * 32 + hl];
    } else { kvA1 = zkv; eaA1 = 0.f; }
    // chunk 1 indices
    es0 = (j0 + 2 < jend) ? eid2[j0 + 2] : make_int2(0, -1);
    es1 = (j0 + 3 < jend) ? eid2[j0 + 3] : make_int2(0, -1);

    int j = j0;
    while (j < jend) {
        // ---- phase A: prefetch next chunk -> B, next-next indices -> es, compute A
        if (es0.y >= 0) {
            kvB0 = *(const u16x8*)(O1 + (size_t)es0.y * 1024 + 256 + lane * 8);
            eaB0 = EA[(size_t)es0.x * 32 + hl];
        } else { kvB0 = zkv; eaB0 = 0.f; }
        if (es1.y >= 0) {
            kvB1 = *(const u16x8*)(O1 + (size_t)es1.y * 1024 + 256 + lane * 8);
            eaB1 = EA[(size_t)es1.x * 32 + hl];
        } else { kvB1 = zkv; eaB1 = 0.f; }
        es0 = (j + 4 < jend) ? eid2[j + 4] : make_int2(0, -1);
        es1 = (j + 5 < jend) ? eid2[j + 5] : make_int2(0, -1);
        {
            float d0 = qv.x*bf2f(kvA0[0]) + qv.y*bf2f(kvA0[1])
                     + qv.z*bf2f(kvA0[2]) + qv.w*bf2f(kvA0[3]) + pd*eaA0;
            float d1 = qv.x*bf2f(kvA1[0]) + qv.y*bf2f(kvA1[1])
                     + qv.z*bf2f(kvA1[2]) + qv.w*bf2f(kvA1[3]) + pd*eaA1;
            #pragma unroll
            for (int off = 16; off >= 1; off >>= 1) {
                d0 += __shfl_xor(d0, off);
                d1 += __shfl_xor(d1, off);
            }
            float w0 = (j     < jend) ? __expf(d0 * inv) : 0.f;
            float w1 = (j + 1 < jend) ? __expf(d1 * inv) : 0.f;
            l += w0 + w1;
            acc.x += w0*bf2f(kvA0[4]) + w1*bf2f(kvA1[4]);
            acc.y += w0*bf2f(kvA0[5]) + w1*bf2f(kvA1[5]);
            acc.z += w0*bf2f(kvA0[6]) + w1*bf2f(kvA1[6]);
            acc.w += w0*bf2f(kvA0[7]) + w1*bf2f(kvA1[7]);
            wacc  += w0*eaA0 + w1*eaA1;
        }
        j += 2;
        if (j >= jend) break;

        // ---- phase B: prefetch -> A, compute B
        if (es0.y >= 0) {
            kvA0 = *(const u16x8*)(O1 + (size_t)es0.y * 1024 + 256 + lane * 8);
            eaA0 = EA[(size_t)es0.x * 32 + hl];
        } else { kvA0 = zkv; eaA0 = 0.f; }
        if (es1.y >= 0) {
            kvA1 = *(const u16x8*)(O1 + (size_t)es1.y * 1024 + 256 + lane * 8);
            eaA1 = EA[(size_t)es1.x * 32 + hl];
        } else { kvA1 = zkv; eaA1 = 0.f; }
        es0 = (j + 4 < jend) ? eid2[j + 4] : make_int2(0, -1);
        es1 = (j + 5 < jend) ? eid2[j + 5] : make_int2(0, -1);
        {
            float d0 = qv.x*bf2f(kvB0[0]) + qv.y*bf2f(kvB0[1])
                     + qv.z*bf2f(kvB0[2]) + qv.w*bf2f(kvB0[3]) + pd*eaB0;
            float d1 = qv.x*bf2f(kvB1[0]) + qv.y*bf2f(kvB1[1])
                     + qv.z*bf2f(kvB1[2]) + qv.w*bf2f(kvB1[3]) + pd*eaB1;
            #pragma unroll
            for (int off = 16; off >= 1; off >>= 1) {
                d0 += __shfl_xor(d0, off);
                d1 += __shfl_xor(d1, off);
            }
            float w0 = (j     < jend) ? __expf(d0 * inv) : 0.f;
            float w1 = (j + 1 < jend) ? __expf(d1 * inv) : 0.f;
            l += w0 + w1;
            acc.x += w0*bf2f(kvB0[4]) + w1*bf2f(kvB1[4]);
            acc.y += w0*bf2f(kvB0[5]) + w1*bf2f(kvB1[5]);
            acc.z += w0*bf2f(kvB0[6]) + w1*bf2f(kvB1[6]);
            acc.w += w0*bf2f(kvB0[7]) + w1*bf2f(kvB1[7]);
            wacc  += w0*eaB0 + w1*eaB1;
        }
        j += 2;
    }
    float r = 1.f / (l + 1e-16f);
    acc.x *= r; acc.y *= r; acc.z *= r; acc.w *= r;
    *(float4*)(agg + (size_t)node * 256 + choff) = acc;
    weab[(size_t)node * 64 + lane] = f2bf(wacc * r);
}

// ---------------- LayerNorm passes ------------------------------------------
__global__ __launch_bounds__(256)
void node_ln1(const float* __restrict__ x, const float* __restrict__ agg,
              const unsigned short* __restrict__ O1, const float* __restrict__ g,
              const float* __restrict__ b, unsigned short* __restrict__ hout, int N) {
    int node = blockIdx.x * 4 + (threadIdx.x >> 6);
    if (node >= N) return;
    int lane = threadIdx.x & 63;
    float2 xv = ((const float2*)(x   + (size_t)node*128))[lane];
    float2 a0 = ((const float2*)(agg + (size_t)node*256))[lane];
    float2 a1 = ((const float2*)(agg + (size_t)node*256 + 128))[lane];
    ushort2 s2 = *(const ushort2*)(O1 + (size_t)node*1024 + 768 + lane*2);
    float t0 = xv.x + 0.5f*(a0.x + a1.x) + bf2f(s2.x);
    float t1 = xv.y + 0.5f*(a0.y + a1.y) + bf2f(s2.y);
    float s = t0 + t1;
    #pragma unroll
    for (int off = 32; off >= 1; off >>= 1) s += __shfl_xor(s, off);
    float mu = s * (1.f/128.f);
    float d0 = t0 - mu, d1 = t1 - mu;
    float q = d0*d0 + d1*d1;
    #pragma unroll
    for (int off = 32; off >= 1; off >>= 1) q += __shfl_xor(q, off);
    float rs = rsqrtf(q * (1.f/128.f) + 1e-5f);
    float2 gv = ((const float2*)g)[lane], bv = ((const float2*)b)[lane];
    ushort2 o;
    o.x = f2bf(d0*rs*gv.x + bv.x);
    o.y = f2bf(d1*rs*gv.y + bv.y);
    *(ushort2*)(hout + (size_t)node*128 + lane*2) = o;
}

__global__ __launch_bounds__(256)
void node_ln2(const unsigned short* __restrict__ hb, const float* __restrict__ f,
              const float* __restrict__ g, const float* __restrict__ b,
              float* __restrict__ out, int N) {
    int node = blockIdx.x * 4 + (threadIdx.x >> 6);
    if (node >= N) return;
    int lane = threadIdx.x & 63;
    ushort2 h2 = *(const ushort2*)(hb + (size_t)node*128 + lane*2);
    float2 fv = ((const float2*)(f + (size_t)node*128))[lane];
    float t0 = bf2f(h2.x) + fv.x;
    float t1 = bf2f(h2.y) + fv.y;
    float s = t0 + t1;
    #pragma unroll
    for (int off = 32; off >= 1; off >>= 1) s += __shfl_xor(s, off);
    float mu = s * (1.f/128.f);
    float d0 = t0 - mu, d1 = t1 - mu;
    float q = d0*d0 + d1*d1;
    #pragma unroll
    for (int off = 32; off >= 1; off >>= 1) q += __shfl_xor(q, off);
    float rs = rsqrtf(q * (1.f/128.f) + 1e-5f);
    float2 gv = ((const float2*)g)[lane], bv = ((const float2*)b)[lane];
    float2 o;
    o.x = d0*rs*gv.x + bv.x;
    o.y = d1*rs*gv.y + bv.y;
    ((float2*)(out + (size_t)node*128))[lane] = o;
}

// ---------------------------------------------------------------------------
extern "C" void kernel_launch(void* const* d_in, const int* in_sizes, int n_in,
                              void* d_out, int out_size, void* d_ws, size_t ws_size,
                              hipStream_t stream) {
    const float* x    = (const float*)d_in[0];
    const int*   ei   = (const int*)d_in[1];
    const float* ea   = (const float*)d_in[2];
    const float* Wq   = (const float*)d_in[3];
    const float* bq   = (const float*)d_in[4];
    const float* Wk   = (const float*)d_in[5];
    const float* bk   = (const float*)d_in[6];
    const float* Wv   = (const float*)d_in[7];
    const float* bv   = (const float*)d_in[8];
    const float* We   = (const float*)d_in[9];
    const float* Wsk  = (const float*)d_in[10];
    const float* bsk  = (const float*)d_in[11];
    const float* g1   = (const float*)d_in[12];
    const float* b1l  = (const float*)d_in[13];
    const float* W1   = (const float*)d_in[14];
    const float* b1f  = (const float*)d_in[15];
    const float* W2   = (const float*)d_in[16];
    const float* b2f  = (const float*)d_in[17];
    const float* g2   = (const float*)d_in[18];
    const float* b2l  = (const float*)d_in[19];
    float* out = (float*)d_out;

    const int N = in_sizes[0] / 128;
    const int E = in_sizes[2] / 32;
    const int* src = ei;
    const int* dst = ei + E;

    char* w = (char*)d_ws;
    unsigned short* O1   = (unsigned short*)w;  w += (size_t)N * 2048;  // [N,1024] bf16
    float* agg           = (float*)w;           w += (size_t)N * 1024;  // [N,256] f32
    unsigned short* weab = (unsigned short*)w;  w += (size_t)N * 128;   // [N,64] bf16
    unsigned short* xh   = (unsigned short*)w;  w += (size_t)N * 256;   // [N,128] bf16
    unsigned short* hb   = (unsigned short*)w;  w += (size_t)N * 256;   // [N,128] bf16
    unsigned short* Wcat = (unsigned short*)w;  w += 1024 * 128 * 2;
    float* bcat          = (float*)w;           w += 1024 * 4;
    unsigned short* W1h  = (unsigned short*)w;  w += 256 * 128 * 2;
    unsigned short* W2h  = (unsigned short*)w;  w += 128 * 256 * 2;
    unsigned short* Wec  = (unsigned short*)w;  w += 256 * 64 * 2;
    int2* eid2           = (int2*)w;            w += (size_t)E * 8;
    int* deg  = (int*)w;
    int* cnt  = deg + N;
    int* tmp  = cnt + N;
    int* rowp = tmp + N;            // N+1
    int* bsum = rowp + N + 1;       // <=1024

    // mid (bf16 [N,256]) and f (f32 [N,128]) alias agg (free after LN1)
    unsigned short* mid = (unsigned short*)agg;
    float* fbuf = (float*)((char*)agg + (size_t)N * 512);

    const int gy128 = (N + 127) / 128;
    const int nb  = (N + 255) / 256;

    // ---- prep ----
    f32_to_bf16<<<(N*128 + 255)/256, 256, 0, stream>>>(x, xh, N*128);
    prep_weights<<<836, 256, 0, stream>>>(Wq, bq, Wk, bk, Wv, bv, We, Wsk, bsk,
                                          W1, W2, Wcat, bcat, W1h, W2h, Wec);

    // ---- fused projection GEMM: O1 = xh @ Wcat^T + bcat ----
    gemm_mfma<0,1,0><<<dim3(8, gy128), 256, 0, stream>>>(xh, 128, Wcat, 128, bcat,
                                                         O1, 1024, N, 128);

    // ---- CSR build ----
    zero_int<<<(2*N + 255)/256, 256, 0, stream>>>(deg, 2*N);   // deg + cnt
    deg_count<<<(E + 255)/256, 256, 0, stream>>>(dst, deg, E);
    scan_block<<<nb, 256, 0, stream>>>(deg, tmp, bsum, N);
    scan_bsum<<<1, 1024, 0, stream>>>(bsum, nb);
    scan_finalize<<<nb, 256, 0, stream>>>(tmp, bsum, rowp, N);
    csr_fill<<<(E + 255)/256, 256, 0, stream>>>(src, dst, rowp, cnt, eid2, E);

    // ---- attention ----
    fused_attn<<<(N + 3)/4, 256, 0, stream>>>(O1, ea, rowp, eid2, agg, weab, N);

    // e-contribution: agg += weab[N,64] @ Wec^T  (block-diag), one MFMA dispatch
    gemm_mfma<0,0,1><<<dim3(2, gy128), 256, 0, stream>>>(weab, 64, Wec, 64, nullptr,
                                                         agg, 256, N, 64);

    // h = LN1(x + mean_heads(agg) + skip) -> bf16
    node_ln1<<<(N + 3)/4, 256, 0, stream>>>(x, agg, O1, g1, b1l, hb, N);

    // FFN (bf16 MFMA)
    gemm_mfma<1,1,0><<<dim3(2, gy128), 256, 0, stream>>>(hb, 128, W1h, 128, b1f,
                                                         mid, 256, N, 128);
    gemm_mfma<0,0,0><<<dim3(1, gy128), 256, 0, stream>>>(mid, 256, W2h, 256, b2f,
                                                         fbuf, 128, N, 256);

    // out = LN2(h + f)
    node_ln2<<<(N + 3)/4, 256, 0, stream>>>(hb, fbuf, g2, b2l, out, N);
}

// Round 6
// 424.723 us; speedup vs baseline: 6.1888x; 1.1269x over previous
//
#include <hip/hip_runtime.h>
#include <hip/hip_bf16.h>

// ---------------------------------------------------------------------------
// GraphTransformerBlock: TransformerConv(H=2, C=128) + skip + LN + FFN + LN
// R6: fused_attn 2 waves/node (additive no-max partials, LDS combine) with
// head-mean folded -> agg[N,128]; LN1 fused into econ GEMM epilogue; LN2
// fused into FFN2 GEMM epilogue; prep+xcast merged. 12 dispatches.
// O1 row [1024]: q 0-255 | kv-interleaved 256-767 | skip 768-895 | P 896-959
//   kv region: for g=0..63 (g=h*32+hl): [256+g*8 .. +3]=k, [+4..+7]=v
// ---------------------------------------------------------------------------

typedef __attribute__((ext_vector_type(8))) short bf16x8;
typedef __attribute__((ext_vector_type(8))) unsigned short u16x8;
typedef __attribute__((ext_vector_type(4))) float f32x4;

__device__ __forceinline__ float bf2f(unsigned short u) {
    union { float f; unsigned u32; } x; x.u32 = ((unsigned)u) << 16; return x.f;
}
__device__ __forceinline__ unsigned short f2bf(float f) {
    unsigned u = __float_as_uint(f);
    return (unsigned short)((u + 0x7FFFu + ((u >> 16) & 1u)) >> 16);
}

// ---------------- bf16 MFMA GEMM + optional fused LN epilogue ---------------
// C[M,OC] = act(A[M,K] @ W[OC,K]^T + bias)
// EPI=0: plain store (bf16 if OUT_BF16 else f32), leaky-relu if ACT.
// EPI=1: (requires grid.x==1, OC=128) t = acc + add0 + add1 + bf16(skip);
//        out = LN(t; g,b) -> bf16.
// EPI=2: (grid.x==1, OC=128) f = acc + bias; t = bf16(hprev) + f;
//        out = LN(t; g,b) -> f32.
template<int ACT, int EPI, int OUT_BF16>
__global__ __launch_bounds__(256)
void gemm_fused(const unsigned short* __restrict__ A, int lda,
                const unsigned short* __restrict__ W, int ldw,
                const float* __restrict__ bias,
                void* __restrict__ outp, int ldo, int M, int K,
                const float* __restrict__ add0, const float* __restrict__ add1,
                const unsigned short* __restrict__ skipp, int skip_ld,
                const unsigned short* __restrict__ hprev,
                const float* __restrict__ lng, const float* __restrict__ lnb) {
    __shared__ unsigned short As[128 * 40];   // pitch 40 elems kills conflicts
    __shared__ unsigned short Bs[128 * 40];
    const int tid = threadIdx.x;
    const int wave = tid >> 6, lane = tid & 63;
    const int row0 = blockIdx.y * 128, col0 = blockIdx.x * 128;
    const int srow = tid >> 2;
    const int skg  = (tid & 3) * 8;
    int r0 = row0 + srow;      if (r0 >= M) r0 = 0;
    int r1 = row0 + srow + 64; if (r1 >= M) r1 = 0;
    const int b0 = col0 + srow, b1 = col0 + srow + 64;

    f32x4 acc[2][8];
    const f32x4 z4 = {0.f, 0.f, 0.f, 0.f};
    #pragma unroll
    for (int i = 0; i < 2; i++)
        #pragma unroll
        for (int j = 0; j < 8; j++) acc[i][j] = z4;

    const int mrow = wave * 32 + (lane & 15);
    const int kq = (lane >> 4) * 8;

    for (int kt = 0; kt < K; kt += 32) {
        float4 a0 = *(const float4*)(A + (size_t)r0 * lda + kt + skg);
        float4 a1 = *(const float4*)(A + (size_t)r1 * lda + kt + skg);
        float4 w0 = *(const float4*)(W + (size_t)b0 * ldw + kt + skg);
        float4 w1 = *(const float4*)(W + (size_t)b1 * ldw + kt + skg);
        __syncthreads();
        *(float4*)&As[srow * 40 + skg]        = a0;
        *(float4*)&As[(srow + 64) * 40 + skg] = a1;
        *(float4*)&Bs[srow * 40 + skg]        = w0;
        *(float4*)&Bs[(srow + 64) * 40 + skg] = w1;
        __syncthreads();
        bf16x8 af0 = *(const bf16x8*)&As[mrow * 40 + kq];
        bf16x8 af1 = *(const bf16x8*)&As[(mrow + 16) * 40 + kq];
        bf16x8 bfr[8];
        #pragma unroll
        for (int j = 0; j < 8; j++)
            bfr[j] = *(const bf16x8*)&Bs[(j * 16 + (lane & 15)) * 40 + kq];
        #pragma unroll
        for (int j = 0; j < 8; j++) {
            acc[0][j] = __builtin_amdgcn_mfma_f32_16x16x32_bf16(af0, bfr[j], acc[0][j], 0, 0, 0);
            acc[1][j] = __builtin_amdgcn_mfma_f32_16x16x32_bf16(af1, bfr[j], acc[1][j], 0, 0, 0);
        }
    }

    // C/D layout: col = lane&15, row = (lane>>4)*4 + reg
    const int lgrp = lane & 15;
    if (EPI == 0) {
        const int orow0 = row0 + wave * 32 + ((lane >> 4) << 2);
        const int ocol0 = col0 + lgrp;
        #pragma unroll
        for (int i = 0; i < 2; i++) {
            #pragma unroll
            for (int r = 0; r < 4; r++) {
                int row = orow0 + i * 16 + r;
                if (row >= M) continue;
                #pragma unroll
                for (int j = 0; j < 8; j++) {
                    int col = ocol0 + j * 16;
                    float v = acc[i][j][r] + (bias ? bias[col] : 0.f);
                    if (ACT == 1) v = (v > 0.f) ? v : 0.01f * v;
                    if (OUT_BF16) ((unsigned short*)outp)[(size_t)row * ldo + col] = f2bf(v);
                    else          ((float*)outp)[(size_t)row * ldo + col] = v;
                }
            }
        }
    } else {
        // full 128-wide row in this block; LN per row across 16-lane group
        #pragma unroll
        for (int i = 0; i < 2; i++) {
            #pragma unroll
            for (int r = 0; r < 4; r++) {
                int row = row0 + wave * 32 + ((lane >> 4) << 2) + i * 16 + r;
                if (row >= M) continue;
                float t[8];
                #pragma unroll
                for (int j = 0; j < 8; j++) {
                    int col = lgrp + j * 16;
                    float v = acc[i][j][r];
                    if (EPI == 1) {
                        v += add0[(size_t)row * 128 + col] + add1[(size_t)row * 128 + col]
                           + bf2f(skipp[(size_t)row * skip_ld + col]);
                    } else {
                        v += bias[col];
                        v += bf2f(hprev[(size_t)row * 128 + col]);
                    }
                    t[j] = v;
                }
                float s = 0.f;
                #pragma unroll
                for (int j = 0; j < 8; j++) s += t[j];
                #pragma unroll
                for (int off = 8; off >= 1; off >>= 1) s += __shfl_xor(s, off);
                float mu = s * (1.f / 128.f);
                float q = 0.f;
                #pragma unroll
                for (int j = 0; j < 8; j++) { float d = t[j] - mu; q += d * d; }
                #pragma unroll
                for (int off = 8; off >= 1; off >>= 1) q += __shfl_xor(q, off);
                float rs = rsqrtf(q * (1.f / 128.f) + 1e-5f);
                #pragma unroll
                for (int j = 0; j < 8; j++) {
                    int col = lgrp + j * 16;
                    float o = (t[j] - mu) * rs * lng[col] + lnb[col];
                    if (EPI == 1) ((unsigned short*)outp)[(size_t)row * ldo + col] = f2bf(o);
                    else          ((float*)outp)[(size_t)row * ldo + col] = o;
                }
            }
        }
    }
}

// ---------------- unified prep: x cast + all weights ------------------------
__global__ void prep_all(const float* __restrict__ x, unsigned short* __restrict__ xh, int NX,
                         const float* __restrict__ Wq, const float* __restrict__ bq,
                         const float* __restrict__ Wk, const float* __restrict__ bk,
                         const float* __restrict__ Wv, const float* __restrict__ bv,
                         const float* __restrict__ We, const float* __restrict__ Wsk,
                         const float* __restrict__ bsk,
                         const float* __restrict__ W1, const float* __restrict__ W2,
                         unsigned short* __restrict__ Wcat, float* __restrict__ bcat,
                         unsigned short* __restrict__ W1h, unsigned short* __restrict__ W2h,
                         unsigned short* __restrict__ Wec2) {
    int i = blockIdx.x * 256 + threadIdx.x;
    if (i < NX) { xh[i] = f2bf(x[i]); return; }
    int k = i - NX;
    if (k < 131072) {                       // Wcat [1024][128]
        int oc = k >> 7, r = k & 127;
        float v;
        if (oc < 256) v = Wq[(size_t)oc * 128 + r];
        else if (oc < 768) {
            int rr = oc - 256, g = rr >> 3, p = rr & 7;
            int h = g >> 5, ch = h * 128 + (g & 31) * 4 + (p & 3);
            v = (p < 4) ? Wk[(size_t)ch * 128 + r] : Wv[(size_t)ch * 128 + r];
        } else if (oc < 896) v = Wsk[(size_t)(oc - 768) * 128 + r];
        else if (oc < 960) {
            int qd = oc - 896, h = qd >> 5, t = qd & 31;
            float s = 0.f;
            for (int c = 0; c < 128; c++)
                s += Wq[(size_t)(h*128 + c) * 128 + r] * We[(size_t)(h*128 + c) * 32 + t];
            v = s;
        } else v = 0.f;
        Wcat[k] = f2bf(v);
    } else if (k < 132096) {                // bcat [1024]
        int oc = k - 131072;
        float v;
        if (oc < 256) v = bq[oc];
        else if (oc < 768) {
            int rr = oc - 256, g = rr >> 3, p = rr & 7;
            int ch = (g >> 5) * 128 + (g & 31) * 4 + (p & 3);
            v = (p < 4) ? bk[ch] : bv[ch];
        } else if (oc < 896) v = bsk[oc - 768];
        else if (oc < 960) {
            int qd = oc - 896, h = qd >> 5, t = qd & 31;
            float s = 0.f;
            for (int c = 0; c < 128; c++)
                s += bq[h*128 + c] * We[(size_t)(h*128 + c) * 32 + t];
            v = s;
        } else v = 0.f;
        bcat[oc] = v;
    } else if (k < 164864) {                // W1h
        int j = k - 132096;
        W1h[j] = f2bf(W1[j]);
    } else if (k < 197632) {                // W2h
        int j = k - 164864;
        W2h[j] = f2bf(W2[j]);
    } else if (k < 205824) {                // Wec2 [128][64], 0.5 head-mean folded
        int j = k - 197632;
        int c = j >> 6, tt = j & 63, h = tt >> 5, t = tt & 31;
        Wec2[j] = f2bf(0.5f * We[(size_t)(h * 128 + c) * 32 + t]);
    }
}

// ---------------- CSR build -------------------------------------------------
__global__ void zero_int(int* __restrict__ p, int n) {
    int i = blockIdx.x * blockDim.x + threadIdx.x;
    if (i < n) p[i] = 0;
}
__global__ void deg_count(const int* __restrict__ dst, int* __restrict__ deg, int E) {
    int e = blockIdx.x * blockDim.x + threadIdx.x;
    if (e < E) atomicAdd(&deg[dst[e]], 1);
}
__global__ __launch_bounds__(256)
void scan_block(const int* __restrict__ deg, int* __restrict__ tmp,
                int* __restrict__ bsum, int n) {
    __shared__ int lds[256];
    int i = blockIdx.x * 256 + threadIdx.x;
    int v = (i < n) ? deg[i] : 0;
    lds[threadIdx.x] = v;
    __syncthreads();
    #pragma unroll
    for (int off = 1; off < 256; off <<= 1) {
        int t = (threadIdx.x >= off) ? lds[threadIdx.x - off] : 0;
        __syncthreads();
        lds[threadIdx.x] += t;
        __syncthreads();
    }
    if (i < n) tmp[i] = lds[threadIdx.x];
    if (threadIdx.x == 255) bsum[blockIdx.x] = lds[255];
}
__global__ __launch_bounds__(1024)
void scan_bsum(int* __restrict__ bsum, int nb) {
    __shared__ int lds[1024];
    int v = (threadIdx.x < nb) ? bsum[threadIdx.x] : 0;
    lds[threadIdx.x] = v;
    __syncthreads();
    #pragma unroll
    for (int off = 1; off < 1024; off <<= 1) {
        int t = (threadIdx.x >= off) ? lds[threadIdx.x - off] : 0;
        __syncthreads();
        lds[threadIdx.x] += t;
        __syncthreads();
    }
    if (threadIdx.x < nb) bsum[threadIdx.x] = lds[threadIdx.x] - v;  // exclusive
}
__global__ __launch_bounds__(256)
void scan_finalize(const int* __restrict__ tmp, const int* __restrict__ bsum,
                   int* __restrict__ row, int n) {
    int i = blockIdx.x * 256 + threadIdx.x;
    if (i < n) row[i + 1] = tmp[i] + bsum[blockIdx.x];
    if (i == 0) row[0] = 0;
}
__global__ void csr_fill(const int* __restrict__ src, const int* __restrict__ dst,
                         const int* __restrict__ row, int* __restrict__ cnt,
                         int2* __restrict__ eid2, int E) {
    int e = blockIdx.x * blockDim.x + threadIdx.x;
    if (e < E) {
        int d = dst[e];
        int pos = row[d] + atomicAdd(&cnt[d], 1);
        eid2[pos] = make_int2(e, src[e]);
    }
}

// ---------------- fused attention: 2 waves/node, static ping-pong -----------
// block = 256 thr = 4 waves = 2 nodes. Wave (node, half) takes 2-edge chunks
// at j0+half*2+4k. Partials additive (no-max softmax); combine via LDS.
// Epilogue: normalize per head, head-mean via shfl_xor(32) -> agg[N,128].
__global__ __launch_bounds__(256)
void fused_attn(const unsigned short* __restrict__ O1, const float* __restrict__ EA,
                const int* __restrict__ row, const int2* __restrict__ eid2,
                float* __restrict__ agg, unsigned short* __restrict__ weab, int N) {
    __shared__ float cb[2][64][6];
    const int wid = threadIdx.x >> 6;
    const int lnode = wid >> 1, half = wid & 1;
    const int node = blockIdx.x * 2 + lnode;
    const int lane = threadIdx.x & 63;
    const int hl = lane & 31;
    const bool active = node < N;
    const float inv = 0.08838834764831845f;  // 1/sqrt(128)

    float l = 0.f, wacc = 0.f;
    float4 acc = make_float4(0.f, 0.f, 0.f, 0.f);

    if (active) {
        const int choff = (lane >> 5) * 128 + (hl << 2);
        ushort4 q4 = *(const ushort4*)(O1 + (size_t)node * 1024 + choff);
        float4 qv = make_float4(bf2f(q4.x), bf2f(q4.y), bf2f(q4.z), bf2f(q4.w));
        float pd = bf2f(O1[(size_t)node * 1024 + 896 + lane]);

        const int jend = row[node + 1];
        int j = row[node] + half * 2;

        const u16x8 zkv = {0,0,0,0,0,0,0,0};
        u16x8 kvA0, kvA1, kvB0, kvB1;
        float eaA0, eaA1, eaB0, eaB1;
        int2 es0, es1;

        if (j < jend) {
            int2 es = eid2[j];
            kvA0 = *(const u16x8*)(O1 + (size_t)es.y * 1024 + 256 + lane * 8);
            eaA0 = EA[(size_t)es.x * 32 + hl];
        } else { kvA0 = zkv; eaA0 = 0.f; }
        if (j + 1 < jend) {
            int2 es = eid2[j + 1];
            kvA1 = *(const u16x8*)(O1 + (size_t)es.y * 1024 + 256 + lane * 8);
            eaA1 = EA[(size_t)es.x * 32 + hl];
        } else { kvA1 = zkv; eaA1 = 0.f; }
        es0 = (j + 4 < jend) ? eid2[j + 4] : make_int2(0, -1);
        es1 = (j + 5 < jend) ? eid2[j + 5] : make_int2(0, -1);

        while (j < jend) {
            // phase A: prefetch chunk j+4 -> B, indices j+8 -> es, compute A
            if (es0.y >= 0) {
                kvB0 = *(const u16x8*)(O1 + (size_t)es0.y * 1024 + 256 + lane * 8);
                eaB0 = EA[(size_t)es0.x * 32 + hl];
            } else { kvB0 = zkv; eaB0 = 0.f; }
            if (es1.y >= 0) {
                kvB1 = *(const u16x8*)(O1 + (size_t)es1.y * 1024 + 256 + lane * 8);
                eaB1 = EA[(size_t)es1.x * 32 + hl];
            } else { kvB1 = zkv; eaB1 = 0.f; }
            es0 = (j + 8 < jend) ? eid2[j + 8] : make_int2(0, -1);
            es1 = (j + 9 < jend) ? eid2[j + 9] : make_int2(0, -1);
            {
                float d0 = qv.x*bf2f(kvA0[0]) + qv.y*bf2f(kvA0[1])
                         + qv.z*bf2f(kvA0[2]) + qv.w*bf2f(kvA0[3]) + pd*eaA0;
                float d1 = qv.x*bf2f(kvA1[0]) + qv.y*bf2f(kvA1[1])
                         + qv.z*bf2f(kvA1[2]) + qv.w*bf2f(kvA1[3]) + pd*eaA1;
                #pragma unroll
                for (int off = 16; off >= 1; off >>= 1) {
                    d0 += __shfl_xor(d0, off);
                    d1 += __shfl_xor(d1, off);
                }
                float w0 = __expf(d0 * inv);
                float w1 = (j + 1 < jend) ? __expf(d1 * inv) : 0.f;
                l += w0 + w1;
                acc.x += w0*bf2f(kvA0[4]) + w1*bf2f(kvA1[4]);
                acc.y += w0*bf2f(kvA0[5]) + w1*bf2f(kvA1[5]);
                acc.z += w0*bf2f(kvA0[6]) + w1*bf2f(kvA1[6]);
                acc.w += w0*bf2f(kvA0[7]) + w1*bf2f(kvA1[7]);
                wacc  += w0*eaA0 + w1*eaA1;
            }
            j += 4;
            if (j >= jend) break;

            // phase B: prefetch chunk j+4 -> A, indices j+8 -> es, compute B
            if (es0.y >= 0) {
                kvA0 = *(const u16x8*)(O1 + (size_t)es0.y * 1024 + 256 + lane * 8);
                eaA0 = EA[(size_t)es0.x * 32 + hl];
            } else { kvA0 = zkv; eaA0 = 0.f; }
            if (es1.y >= 0) {
                kvA1 = *(const u16x8*)(O1 + (size_t)es1.y * 1024 + 256 + lane * 8);
                eaA1 = EA[(size_t)es1.x * 32 + hl];
            } else { kvA1 = zkv; eaA1 = 0.f; }
            es0 = (j + 8 < jend) ? eid2[j + 8] : make_int2(0, -1);
            es1 = (j + 9 < jend) ? eid2[j + 9] : make_int2(0, -1);
            {
                float d0 = qv.x*bf2f(kvB0[0]) + qv.y*bf2f(kvB0[1])
                         + qv.z*bf2f(kvB0[2]) + qv.w*bf2f(kvB0[3]) + pd*eaB0;
                float d1 = qv.x*bf2f(kvB1[0]) + qv.y*bf2f(kvB1[1])
                         + qv.z*bf2f(kvB1[2]) + qv.w*bf2f(kvB1[3]) + pd*eaB1;
                #pragma unroll
                for (int off = 16; off >= 1; off >>= 1) {
                    d0 += __shfl_xor(d0, off);
                    d1 += __shfl_xor(d1, off);
                }
                float w0 = __expf(d0 * inv);
                float w1 = (j + 1 < jend) ? __expf(d1 * inv) : 0.f;
                l += w0 + w1;
                acc.x += w0*bf2f(kvB0[4]) + w1*bf2f(kvB1[4]);
                acc.y += w0*bf2f(kvB0[5]) + w1*bf2f(kvB1[5]);
                acc.z += w0*bf2f(kvB0[6]) + w1*bf2f(kvB1[6]);
                acc.w += w0*bf2f(kvB0[7]) + w1*bf2f(kvB1[7]);
                wacc  += w0*eaB0 + w1*eaB1;
            }
            j += 4;
        }
    }

    if (half == 1) {
        cb[lnode][lane][0] = acc.x; cb[lnode][lane][1] = acc.y;
        cb[lnode][lane][2] = acc.z; cb[lnode][lane][3] = acc.w;
        cb[lnode][lane][4] = wacc;  cb[lnode][lane][5] = l;
    }
    __syncthreads();
    if (half == 0 && active) {
        acc.x += cb[lnode][lane][0]; acc.y += cb[lnode][lane][1];
        acc.z += cb[lnode][lane][2]; acc.w += cb[lnode][lane][3];
        wacc  += cb[lnode][lane][4]; l += cb[lnode][lane][5];
        float r = 1.f / (l + 1e-16f);
        acc.x *= r; acc.y *= r; acc.z *= r; acc.w *= r;
        weab[(size_t)node * 64 + lane] = f2bf(wacc * r);
        float mx = 0.5f * (acc.x + __shfl_xor(acc.x, 32));
        float my = 0.5f * (acc.y + __shfl_xor(acc.y, 32));
        float mz = 0.5f * (acc.z + __shfl_xor(acc.z, 32));
        float mw = 0.5f * (acc.w + __shfl_xor(acc.w, 32));
        if (lane < 32)
            *(float4*)(agg + (size_t)node * 128 + hl * 4) = make_float4(mx, my, mz, mw);
    }
}

// ---------------------------------------------------------------------------
extern "C" void kernel_launch(void* const* d_in, const int* in_sizes, int n_in,
                              void* d_out, int out_size, void* d_ws, size_t ws_size,
                              hipStream_t stream) {
    const float* x    = (const float*)d_in[0];
    const int*   ei   = (const int*)d_in[1];
    const float* ea   = (const float*)d_in[2];
    const float* Wq   = (const float*)d_in[3];
    const float* bq   = (const float*)d_in[4];
    const float* Wk   = (const float*)d_in[5];
    const float* bk   = (const float*)d_in[6];
    const float* Wv   = (const float*)d_in[7];
    const float* bv   = (const float*)d_in[8];
    const float* We   = (const float*)d_in[9];
    const float* Wsk  = (const float*)d_in[10];
    const float* bsk  = (const float*)d_in[11];
    const float* g1   = (const float*)d_in[12];
    const float* b1l  = (const float*)d_in[13];
    const float* W1   = (const float*)d_in[14];
    const float* b1f  = (const float*)d_in[15];
    const float* W2   = (const float*)d_in[16];
    const float* b2f  = (const float*)d_in[17];
    const float* g2   = (const float*)d_in[18];
    const float* b2l  = (const float*)d_in[19];
    float* out = (float*)d_out;

    const int N = in_sizes[0] / 128;
    const int E = in_sizes[2] / 32;
    const int* src = ei;
    const int* dst = ei + E;

    char* w = (char*)d_ws;
    unsigned short* O1   = (unsigned short*)w;  w += (size_t)N * 2048;  // [N,1024] bf16
    float* agg           = (float*)w;           w += (size_t)N * 512;   // [N,128] f32
    unsigned short* weab = (unsigned short*)w;  w += (size_t)N * 128;   // [N,64] bf16
    unsigned short* xh   = (unsigned short*)w;  w += (size_t)N * 256;   // [N,128] bf16
    unsigned short* hb   = (unsigned short*)w;  w += (size_t)N * 256;   // [N,128] bf16
    unsigned short* Wcat = (unsigned short*)w;  w += 1024 * 128 * 2;
    float* bcat          = (float*)w;           w += 1024 * 4;
    unsigned short* W1h  = (unsigned short*)w;  w += 256 * 128 * 2;
    unsigned short* W2h  = (unsigned short*)w;  w += 128 * 256 * 2;
    unsigned short* Wec2 = (unsigned short*)w;  w += 128 * 64 * 2;
    int2* eid2           = (int2*)w;            w += (size_t)E * 8;
    int* deg  = (int*)w;
    int* cnt  = deg + N;
    int* tmp  = cnt + N;
    int* rowp = tmp + N;            // N+1
    int* bsum = rowp + N + 1;       // <=1024

    // mid (bf16 [N,256] = N*512 B) aliases agg (free after econ+LN1)
    unsigned short* mid = (unsigned short*)agg;

    const int gy128 = (N + 127) / 128;
    const int nb = (N + 255) / 256;
    const int NX = N * 128;

    // ---- prep: x cast + all weights, one dispatch ----
    prep_all<<<(NX + 205824 + 255) / 256, 256, 0, stream>>>(
        x, xh, NX, Wq, bq, Wk, bk, Wv, bv, We, Wsk, bsk, W1, W2,
        Wcat, bcat, W1h, W2h, Wec2);

    // ---- fused projection GEMM: O1 = xh @ Wcat^T + bcat ----
    gemm_fused<0,0,1><<<dim3(8, gy128), 256, 0, stream>>>(
        xh, 128, Wcat, 128, bcat, O1, 1024, N, 128,
        nullptr, nullptr, nullptr, 0, nullptr, nullptr, nullptr);

    // ---- CSR build ----
    zero_int<<<(2*N + 255)/256, 256, 0, stream>>>(deg, 2*N);   // deg + cnt
    deg_count<<<(E + 255)/256, 256, 0, stream>>>(dst, deg, E);
    scan_block<<<nb, 256, 0, stream>>>(deg, tmp, bsum, N);
    scan_bsum<<<1, 1024, 0, stream>>>(bsum, nb);
    scan_finalize<<<nb, 256, 0, stream>>>(tmp, bsum, rowp, N);
    csr_fill<<<(E + 255)/256, 256, 0, stream>>>(src, dst, rowp, cnt, eid2, E);

    // ---- attention (2 waves/node) ----
    fused_attn<<<(N + 1) / 2, 256, 0, stream>>>(O1, ea, rowp, eid2, agg, weab, N);

    // ---- econ GEMM + LN1 fused: hb = LN1(weab@Wec2^T + agg + x + skip) ----
    gemm_fused<0,1,1><<<dim3(1, gy128), 256, 0, stream>>>(
        weab, 64, Wec2, 64, nullptr, hb, 128, N, 64,
        agg, x, O1 + 768, 1024, nullptr, g1, b1l);

    // ---- FFN1: mid = leaky(hb @ W1h^T + b1f) ----
    gemm_fused<1,0,1><<<dim3(2, gy128), 256, 0, stream>>>(
        hb, 128, W1h, 128, b1f, mid, 256, N, 128,
        nullptr, nullptr, nullptr, 0, nullptr, nullptr, nullptr);

    // ---- FFN2 + LN2 fused: out = LN2(hb + mid @ W2h^T + b2f) ----
    gemm_fused<0,2,0><<<dim3(1, gy128), 256, 0, stream>>>(
        mid, 256, W2h, 256, b2f, out, 128, N, 256,
        nullptr, nullptr, nullptr, 0, hb, g2, b2l);
}